// Round 3
// baseline (309.060 us; speedup 1.0000x reference)
//
#include <hip/hip_runtime.h>

#define LSIZE 24
#define VOL (LSIZE*LSIZE*LSIZE*LSIZE)       // 331776 sites
#define NLINES (LSIZE*LSIZE*LSIZE)          // 13824 lines per direction
#define LPB 8                               // lines per thread-group
#define GPB 2                               // groups per block
#define TPG (LPB*LSIZE)                     // 192 threads per group (3 waves)
#define TPB (GPB*TPG)                       // 384 threads per block
#define MSTRIDE 19                          // floats per matrix-half slot (pad 18->19: 2-way banks only)

__device__ __forceinline__ void copy9(float* d, const float* s) {
#pragma unroll
  for (int e = 0; e < 9; ++e) d[e] = s[e];
}

// (o_re,o_im) = a * b, complex 3x3 matmul (row-major)
__device__ __forceinline__ void cmul(const float* ar, const float* ai,
                                     const float* br, const float* bi,
                                     float* or_, float* oi_) {
#pragma unroll
  for (int i = 0; i < 3; ++i) {
#pragma unroll
    for (int j = 0; j < 3; ++j) {
      float sr = 0.f, si = 0.f;
#pragma unroll
      for (int m = 0; m < 3; ++m) {
        float x = ar[i*3+m], y = ai[i*3+m];
        float u = br[m*3+j], v = bi[m*3+j];
        sr = fmaf(x, u, sr);
        sr = fmaf(-y, v, sr);
        si = fmaf(x, v, si);
        si = fmaf(y, u, si);
      }
      or_[i*3+j] = sr;
      oi_[i*3+j] = si;
    }
  }
}

// matrix slot = 2*MSTRIDE floats (re block + im block), b32 accesses only
__device__ __forceinline__ void lds_put(float* lds, int slot, const float* re, const float* im) {
  float* p = lds + slot * (2*MSTRIDE);
#pragma unroll
  for (int e = 0; e < 9; ++e) { p[e] = re[e]; p[MSTRIDE+e] = im[e]; }
}
__device__ __forceinline__ void lds_get(const float* lds, int slot, float* re, float* im) {
  const float* p = lds + slot * (2*MSTRIDE);
#pragma unroll
  for (int e = 0; e < 9; ++e) { re[e] = p[e]; im[e] = p[MSTRIDE+e]; }
}

// One thread per (direction, line, offset k). Per line: Hillis-Steele prefix
// scan A_k = U_0..U_k and suffix scan S_k = U_k..U_23 in LDS, then
// P(k) = S_k * A_{k-1} (A_{-1} = I).
__global__ __launch_bounds__(TPB, 2) void polyakov_scan(
    const float* __restrict__ U_re, const float* __restrict__ U_im,
    float* __restrict__ out) {
  __shared__ float lds[GPB * LPB * LSIZE * 2 * MSTRIDE];   // 29184 B

  int tid   = threadIdx.x;
  int group = tid / TPG;
  int gt    = tid - group * TPG;
  int lineLocal = gt % LPB;     // fast index within wave
  int k = gt / LPB;             // offset along the line, 0..23
  float* glds = lds + group * (LPB * LSIZE * 2 * MSTRIDE);

  int L = blockIdx.x * (GPB*LPB) + group * LPB + lineLocal;
  int mu = L / NLINES;
  int l  = L - mu * NLINES;
  int cC = l % LSIZE;
  int cB = (l / LSIZE) % LSIZE;
  int cA = l / (LSIZE*LSIZE);

  int x0, x1, x2, x3, st;
  if (mu == 0)      { x0 = 0;  x1 = cA; x2 = cB; x3 = cC; st = LSIZE*LSIZE*LSIZE; }
  else if (mu == 1) { x0 = cA; x1 = 0;  x2 = cB; x3 = cC; st = LSIZE*LSIZE; }
  else if (mu == 2) { x0 = cA; x1 = cB; x2 = 0;  x3 = cC; st = LSIZE; }
  else              { x0 = cA; x1 = cB; x2 = cC; x3 = 0;  st = 1; }
  int s0 = ((x0*LSIZE + x1)*LSIZE + x2)*LSIZE + x3;
  int site = s0 + k * st;

  const float* inR = U_re + (size_t)mu * (VOL*9) + (size_t)site * 9;
  const float* inI = U_im + (size_t)mu * (VOL*9) + (size_t)site * 9;

  float Ur[9], Ui[9];
#pragma unroll
  for (int e = 0; e < 9; ++e) { Ur[e] = inR[e]; Ui[e] = inI[e]; }

  int slot = lineLocal * LSIZE + k;
  float Ar[9], Ai[9], Br[9], Bi[9], Tr[9], Ti[9];

  // ---- prefix scan: A_k = U_0 ... U_k ----
  copy9(Ar, Ur); copy9(Ai, Ui);
#pragma unroll
  for (int d = 1; d < LSIZE; d <<= 1) {
    lds_put(glds, slot, Ar, Ai);
    __syncthreads();
    if (k >= d) lds_get(glds, lineLocal * LSIZE + (k - d), Br, Bi);
    __syncthreads();
    if (k >= d) {
      cmul(Br, Bi, Ar, Ai, Tr, Ti);   // A_new = A[k-d] * A[k]
      copy9(Ar, Tr); copy9(Ai, Ti);
    }
  }
  // publish final prefixes, grab A_{k-1}
  lds_put(glds, slot, Ar, Ai);
  __syncthreads();
  float Apr[9], Api[9];
  if (k >= 1) {
    lds_get(glds, lineLocal * LSIZE + (k - 1), Apr, Api);
  } else {
#pragma unroll
    for (int e = 0; e < 9; ++e) { Apr[e] = (e == 0 || e == 4 || e == 8) ? 1.f : 0.f; Api[e] = 0.f; }
  }
  __syncthreads();

  // ---- suffix scan: S_k = U_k ... U_23 (reuse Ar/Ai as S) ----
  copy9(Ar, Ur); copy9(Ai, Ui);
#pragma unroll
  for (int d = 1; d < LSIZE; d <<= 1) {
    lds_put(glds, slot, Ar, Ai);
    __syncthreads();
    if (k + d < LSIZE) lds_get(glds, lineLocal * LSIZE + (k + d), Br, Bi);
    __syncthreads();
    if (k + d < LSIZE) {
      cmul(Ar, Ai, Br, Bi, Tr, Ti);   // S_new = S[k] * S[k+d]
      copy9(Ar, Tr); copy9(Ai, Ti);
    }
  }

  // ---- P(k) = S_k * A_{k-1} ----
  cmul(Ar, Ai, Apr, Api, Tr, Ti);

  float* outR = out + (size_t)mu * (VOL*9) + (size_t)site * 9;
  float* outI = out + (size_t)(4 + mu) * (VOL*9) + (size_t)site * 9;
#pragma unroll
  for (int e = 0; e < 9; ++e) { outR[e] = Tr[e]; outI[e] = Ti[e]; }
}

extern "C" void kernel_launch(void* const* d_in, const int* in_sizes, int n_in,
                              void* d_out, int out_size, void* d_ws, size_t ws_size,
                              hipStream_t stream) {
  const float* U_re = (const float*)d_in[0];
  const float* U_im = (const float*)d_in[1];
  float* out = (float*)d_out;
  int nblocks = 4 * NLINES / (GPB * LPB);   // 3456
  hipLaunchKernelGGL(polyakov_scan, dim3(nblocks), dim3(TPB), 0, stream, U_re, U_im, out);
}

// Round 4
// 189.113 us; speedup vs baseline: 1.6343x; 1.6343x over previous
//
#include <hip/hip_runtime.h>

#define LSIZE 24
#define VOL (LSIZE*LSIZE*LSIZE*LSIZE)       // 331776 sites
#define NLINES (LSIZE*LSIZE*LSIZE)          // 13824 lines per direction
#define LPB 8                               // lines per block
#define TPB (LPB*LSIZE)                     // 192 threads = 3 waves
#define NSLOT TPB                           // one LDS slot per thread

__device__ __forceinline__ void copy9(float* d, const float* s) {
#pragma unroll
  for (int e = 0; e < 9; ++e) d[e] = s[e];
}

// (o_re,o_im) = a * b, complex 3x3 matmul (row-major)
__device__ __forceinline__ void cmul(const float* ar, const float* ai,
                                     const float* br, const float* bi,
                                     float* or_, float* oi_) {
#pragma unroll
  for (int i = 0; i < 3; ++i) {
#pragma unroll
    for (int j = 0; j < 3; ++j) {
      float sr = 0.f, si = 0.f;
#pragma unroll
      for (int m = 0; m < 3; ++m) {
        float x = ar[i*3+m], y = ai[i*3+m];
        float u = br[m*3+j], v = bi[m*3+j];
        sr = fmaf(x, u, sr);
        sr = fmaf(-y, v, sr);
        si = fmaf(x, v, si);
        si = fmaf(y, u, si);
      }
      or_[i*3+j] = sr;
      oi_[i*3+j] = si;
    }
  }
}

// Element-major LDS: plane e holds element e for all 192 slots.
// addr = e*NSLOT + slot; lanes have consecutive slot -> consecutive banks
// -> exactly 2 lanes/bank (free on gfx950).
__device__ __forceinline__ void lds_put(float* lds, int slot, const float* re, const float* im) {
#pragma unroll
  for (int e = 0; e < 9; ++e) {
    lds[e * NSLOT + slot]       = re[e];
    lds[(9 + e) * NSLOT + slot] = im[e];
  }
}
__device__ __forceinline__ void lds_get(const float* lds, int slot, float* re, float* im) {
#pragma unroll
  for (int e = 0; e < 9; ++e) {
    re[e] = lds[e * NSLOT + slot];
    im[e] = lds[(9 + e) * NSLOT + slot];
  }
}

// One thread per (direction, line, offset k). Per line: Hillis-Steele prefix
// scan A_k = U_0..U_k and suffix scan S_k = U_k..U_23 in LDS, then
// P(k) = S_k * A_{k-1} (A_{-1} = I).
// slot = gt = k*LPB + lineLocal; neighbor (k-d) is slot - 8d.
__global__ __launch_bounds__(TPB, 4) void polyakov_scan(
    const float* __restrict__ U_re, const float* __restrict__ U_im,
    float* __restrict__ out) {
  __shared__ float lds[18 * NSLOT];   // 13824 B

  int gt = threadIdx.x;
  int lineLocal = gt % LPB;     // fast index -> coalesced global access
  int k = gt / LPB;             // offset along the line, 0..23
  int slot = gt;

  int L = blockIdx.x * LPB + lineLocal;
  int mu = L / NLINES;
  int l  = L - mu * NLINES;
  int cC = l % LSIZE;
  int cB = (l / LSIZE) % LSIZE;
  int cA = l / (LSIZE*LSIZE);

  int x0, x1, x2, x3, st;
  if (mu == 0)      { x0 = 0;  x1 = cA; x2 = cB; x3 = cC; st = LSIZE*LSIZE*LSIZE; }
  else if (mu == 1) { x0 = cA; x1 = 0;  x2 = cB; x3 = cC; st = LSIZE*LSIZE; }
  else if (mu == 2) { x0 = cA; x1 = cB; x2 = 0;  x3 = cC; st = LSIZE; }
  else              { x0 = cA; x1 = cB; x2 = cC; x3 = 0;  st = 1; }
  int s0 = ((x0*LSIZE + x1)*LSIZE + x2)*LSIZE + x3;
  int site = s0 + k * st;

  const float* inR = U_re + (size_t)mu * (VOL*9) + (size_t)site * 9;
  const float* inI = U_im + (size_t)mu * (VOL*9) + (size_t)site * 9;

  float Ur[9], Ui[9];
#pragma unroll
  for (int e = 0; e < 9; ++e) { Ur[e] = inR[e]; Ui[e] = inI[e]; }

  float Ar[9], Ai[9], Br[9], Bi[9], Tr[9], Ti[9];

  // ---- prefix scan: A_k = U_0 ... U_k ----
  copy9(Ar, Ur); copy9(Ai, Ui);
#pragma unroll
  for (int d = 1; d < LSIZE; d <<= 1) {
    lds_put(lds, slot, Ar, Ai);
    __syncthreads();
    if (k >= d) lds_get(lds, slot - d * LPB, Br, Bi);
    __syncthreads();
    if (k >= d) {
      cmul(Br, Bi, Ar, Ai, Tr, Ti);   // A_new = A[k-d] * A[k]
      copy9(Ar, Tr); copy9(Ai, Ti);
    }
  }
  // publish final prefixes, grab A_{k-1}
  lds_put(lds, slot, Ar, Ai);
  __syncthreads();
  float Apr[9], Api[9];
  if (k >= 1) {
    lds_get(lds, slot - LPB, Apr, Api);
  } else {
#pragma unroll
    for (int e = 0; e < 9; ++e) { Apr[e] = (e == 0 || e == 4 || e == 8) ? 1.f : 0.f; Api[e] = 0.f; }
  }
  __syncthreads();

  // ---- suffix scan: S_k = U_k ... U_23 (reuse Ar/Ai as S) ----
  copy9(Ar, Ur); copy9(Ai, Ui);
#pragma unroll
  for (int d = 1; d < LSIZE; d <<= 1) {
    lds_put(lds, slot, Ar, Ai);
    __syncthreads();
    if (k + d < LSIZE) lds_get(lds, slot + d * LPB, Br, Bi);
    __syncthreads();
    if (k + d < LSIZE) {
      cmul(Ar, Ai, Br, Bi, Tr, Ti);   // S_new = S[k] * S[k+d]
      copy9(Ar, Tr); copy9(Ai, Ti);
    }
  }

  // ---- P(k) = S_k * A_{k-1} ----
  cmul(Ar, Ai, Apr, Api, Tr, Ti);

  float* outR = out + (size_t)mu * (VOL*9) + (size_t)site * 9;
  float* outI = out + (size_t)(4 + mu) * (VOL*9) + (size_t)site * 9;
#pragma unroll
  for (int e = 0; e < 9; ++e) { outR[e] = Tr[e]; outI[e] = Ti[e]; }
}

extern "C" void kernel_launch(void* const* d_in, const int* in_sizes, int n_in,
                              void* d_out, int out_size, void* d_ws, size_t ws_size,
                              hipStream_t stream) {
  const float* U_re = (const float*)d_in[0];
  const float* U_im = (const float*)d_in[1];
  float* out = (float*)d_out;
  int nblocks = 4 * NLINES / LPB;   // 6912
  hipLaunchKernelGGL(polyakov_scan, dim3(nblocks), dim3(TPB), 0, stream, U_re, U_im, out);
}